// Round 11
// baseline (148.945 us; speedup 1.0000x reference)
//
#include <hip/hip_runtime.h>

#define NBLK 256

typedef float f2 __attribute__((ext_vector_type(2)));   // VGPR pair -> VOP3P v_pk_* f32

#if __has_builtin(__builtin_elementwise_fma)
__device__ __forceinline__ f2 pk_fma(f2 a, f2 b, f2 c) { return __builtin_elementwise_fma(a, b, c); }
#else
__device__ __forceinline__ f2 pk_fma(f2 a, f2 b, f2 c) {
    f2 r; r.x = fmaf(a.x, b.x, c.x); r.y = fmaf(a.y, b.y, c.y); return r;
}
#endif

// packed tanh(z) and 1-tanh^2: tanh = 1 - 2/(exp2(2*log2e*z)+1). abs err ~3e-7.
__device__ __forceinline__ void tanh2(const f2 z, f2& th, f2& om) {
    const f2 zz = z * 2.88539008f;
    f2 s;
    s.x = __builtin_amdgcn_rcpf(__builtin_amdgcn_exp2f(zz.x) + 1.0f);
    s.y = __builtin_amdgcn_rcpf(__builtin_amdgcn_exp2f(zz.y) + 1.0f);
    th = 1.0f - 2.0f * s;
    om = 1.0f - th * th;
}

__global__ __launch_bounds__(NBLK) void pinn_kernel(
    const float* __restrict__ T,
    const float* __restrict__ W1, const float* __restrict__ b1,
    const float* __restrict__ W2, const float* __restrict__ b2,
    const float* __restrict__ W3, const float* __restrict__ b3,
    const float* __restrict__ W4, const float* __restrict__ b4,
    const float* __restrict__ Wo, const float* __restrict__ bo,
    const float* __restrict__ C1, const float* __restrict__ C2, const float* __restrict__ C3,
    float* __restrict__ out, int n)
{
    // 2 points per lane (A = even point, B = odd). No LDS; weights stream on the
    // scalar/SMEM pipe. Per-point SMEM traffic and wave-fixed costs halve vs 1pt/lane.
    const int i0 = blockIdx.x * NBLK + threadIdx.x;
    const int p0 = i0 * 2;
    const int pc = (p0 + 1 < n) ? p0 : (n >= 2 ? n - 2 : 0);   // clamped load base
    const float2 tt = *reinterpret_cast<const float2*>(T + pc);
    const f2 tA = {tt.x, tt.x};
    const f2 tB = {tt.y, tt.y};

    // State as j-pairs: H*[jj] = (h[2jj], h[2jj+1]) for point A / B.
    f2 HA[10], HB[10], DA[10], DB[10];

    // ---- layer 1: z = t*W1 + b1, dz = W1 (tangent dt = 1) ----
#pragma unroll
    for (int jj = 0; jj < 10; ++jj) {
        const f2 w = *reinterpret_cast<const f2*>(W1 + 2 * jj);   // uniform -> s_load pair
        const f2 b = *reinterpret_cast<const f2*>(b1 + 2 * jj);
        f2 thA, omA, thB, omB;
        tanh2(pk_fma(tA, w, b), thA, omA);
        tanh2(pk_fma(tB, w, b), thB, omB);
        HA[jj] = thA;  DA[jj] = omA * w;
        HB[jj] = thB;  DB[jj] = omB * w;
    }

    // ---- layers 2..4: k-outer / jj-inner; 4 pk_fma per (k,jj) [2 points x 2 streams] ----
#pragma unroll 1
    for (int L = 0; L < 3; ++L) {
        const float* __restrict__ WP = (L == 0) ? W2 : (L == 1) ? W3 : W4;
        const float* __restrict__ BP = (L == 0) ? b2 : (L == 1) ? b3 : b4;
        f2 AA[10], AB[10], DDA[10], DDB[10];
#pragma unroll
        for (int jj = 0; jj < 10; ++jj) {
            const f2 b = *reinterpret_cast<const f2*>(BP + 2 * jj);
            AA[jj] = b;  AB[jj] = b;
            DDA[jj] = (f2){0.0f, 0.0f};
            DDB[jj] = (f2){0.0f, 0.0f};
        }
#pragma unroll
        for (int k = 0; k < 20; ++k) {
            const float hkA = (k & 1) ? HA[k >> 1].y : HA[k >> 1].x;   // static extract
            const float dkA = (k & 1) ? DA[k >> 1].y : DA[k >> 1].x;
            const float hkB = (k & 1) ? HB[k >> 1].y : HB[k >> 1].x;
            const float dkB = (k & 1) ? DB[k >> 1].y : DB[k >> 1].x;
            const f2 hA2 = {hkA, hkA}, dA2 = {dkA, dkA};
            const f2 hB2 = {hkB, hkB}, dB2 = {dkB, dkB};
#pragma unroll
            for (int jj = 0; jj < 10; ++jj) {
                const f2 w2 = *reinterpret_cast<const f2*>(WP + k * 20 + 2 * jj);
                AA[jj]  = pk_fma(hA2, w2, AA[jj]);
                DDA[jj] = pk_fma(dA2, w2, DDA[jj]);
                AB[jj]  = pk_fma(hB2, w2, AB[jj]);
                DDB[jj] = pk_fma(dB2, w2, DDB[jj]);
            }
        }
#pragma unroll
        for (int jj = 0; jj < 10; ++jj) {
            f2 th, om;
            tanh2(AA[jj], th, om);
            HA[jj] = th;  DA[jj] = om * DDA[jj];
            tanh2(AB[jj], th, om);
            HB[jj] = th;  DB[jj] = om * DDB[jj];
        }
    }

    // ---- output layer: o = h@Wo + bo, go = d@Wo.  acc as f2 per point: (o_w0-pair etc.)
    // Wo row k = 3 floats; process scalar per point (120 FMA / 2 pts, small).
    float oA0 = bo[0], oA1 = bo[1], oA2 = bo[2], gA0 = 0.f, gA1 = 0.f, gA2 = 0.f;
    float oB0 = bo[0], oB1 = bo[1], oB2 = bo[2], gB0 = 0.f, gB1 = 0.f, gB2 = 0.f;
#pragma unroll
    for (int k = 0; k < 20; ++k) {
        const float hkA = (k & 1) ? HA[k >> 1].y : HA[k >> 1].x;
        const float dkA = (k & 1) ? DA[k >> 1].y : DA[k >> 1].x;
        const float hkB = (k & 1) ? HB[k >> 1].y : HB[k >> 1].x;
        const float dkB = (k & 1) ? DB[k >> 1].y : DB[k >> 1].x;
        const float w0 = Wo[k * 3 + 0];
        const float w1 = Wo[k * 3 + 1];
        const float w2 = Wo[k * 3 + 2];
        oA0 = fmaf(hkA, w0, oA0);  gA0 = fmaf(dkA, w0, gA0);
        oA1 = fmaf(hkA, w1, oA1);  gA1 = fmaf(dkA, w1, gA1);
        oA2 = fmaf(hkA, w2, oA2);  gA2 = fmaf(dkA, w2, gA2);
        oB0 = fmaf(hkB, w0, oB0);  gB0 = fmaf(dkB, w0, gB0);
        oB1 = fmaf(hkB, w1, oB1);  gB1 = fmaf(dkB, w1, gB1);
        oB2 = fmaf(hkB, w2, oB2);  gB2 = fmaf(dkB, w2, gB2);
    }

    const float c1 = C1[0], c2 = C2[0], c3 = C3[0];
    const float fxA = gA0 - c1 * (oA1 - oA0);
    const float fyA = gA1 - oA0 * (c2 - oA2) + oA1;
    const float fzA = gA2 - oA0 * oA1 + c3 * oA2;
    const float fxB = gB0 - c1 * (oB1 - oB0);
    const float fyB = gB1 - oB0 * (c2 - oB2) + oB1;
    const float fzB = gB2 - oB0 * oB1 + c3 * oB2;

    if (p0 + 1 < n) {
        // 12 contiguous floats (48B, 16B-aligned since p0 even) -> 3x dwordx4
        float4* po = reinterpret_cast<float4*>(out + (size_t)p0 * 6);
        po[0] = make_float4(oA0, oA1, oA2, fxA);
        po[1] = make_float4(fyA, fzA, oB0, oB1);
        po[2] = make_float4(oB2, fxB, fyB, fzB);
    } else if (p0 < n) {
        float2* po = reinterpret_cast<float2*>(out + (size_t)p0 * 6);
        po[0] = make_float2(oA0, oA1);
        po[1] = make_float2(oA2, fxA);
        po[2] = make_float2(fyA, fzA);
    }
}

extern "C" void kernel_launch(void* const* d_in, const int* in_sizes, int n_in,
                              void* d_out, int out_size, void* d_ws, size_t ws_size,
                              hipStream_t stream) {
    const float* T  = (const float*)d_in[0];
    const float* W1 = (const float*)d_in[1];
    const float* b1 = (const float*)d_in[2];
    const float* W2 = (const float*)d_in[3];
    const float* b2 = (const float*)d_in[4];
    const float* W3 = (const float*)d_in[5];
    const float* b3 = (const float*)d_in[6];
    const float* W4 = (const float*)d_in[7];
    const float* b4 = (const float*)d_in[8];
    const float* Wo = (const float*)d_in[9];
    const float* bo = (const float*)d_in[10];
    const float* C1 = (const float*)d_in[11];
    const float* C2 = (const float*)d_in[12];
    const float* C3 = (const float*)d_in[13];
    float* out = (float*)d_out;

    const int n = in_sizes[0];
    const int npairs = (n + 1) / 2;
    const int blocks = (npairs + NBLK - 1) / NBLK;
    pinn_kernel<<<blocks, NBLK, 0, stream>>>(T, W1, b1, W2, b2, W3, b3, W4, b4,
                                             Wo, bo, C1, C2, C3, out, n);
}